// Round 2
// baseline (2217.779 us; speedup 1.0000x reference)
//
#include <hip/hip_runtime.h>
#include <stdint.h>

typedef unsigned short u16;
typedef unsigned int u32;

#define L_STEPS 64
#define B_SZ 32
#define H_SZ 256
#define Z_SZ 256
#define V_SZ 32000
#define H2 128          // H/2 (f16 pairs per row)
#define G3H 768         // 3*H

typedef _Float16 h2_t __attribute__((ext_vector_type(2)));

// ---- workspace layout in h2_t units (4 bytes each) ----
#define WHH2_OFF   0            // 4 mats x 98304 (enc_c, enc_s, dec_c, dec_s)
#define WIH2_OFF   393216       // 4 mats x 98304
#define WM2_OFF    786432       // 32768
#define WLV2_OFF   819200       // 32768
#define WL2H2_OFF  851968       // 32768
#define GI2_OFF    884736       // f16 gi: 4*2048*384 = 3,145,728 h2
#define OUTS2_OFF  4030464      // 2048*128 = 262,144 h2
// total 4,292,608 h2 = 17.2 MB

// ---- d_out layout (fp32 elements) ----
#define OUT_MEAN_OFF  65536000
#define OUT_LOGV_OFF  65544192
#define OUT_Z_OFF     65552384

__device__ __forceinline__ float fdot2(h2_t a, h2_t b, float c){
#if __has_builtin(__builtin_amdgcn_fdot2)
  return __builtin_amdgcn_fdot2(a, b, c, false);
#else
  return c + (float)a.x*(float)b.x + (float)a.y*(float)b.y;
#endif
}
__device__ __forceinline__ float sigm(float x){ return 1.f/(1.f + __expf(-x)); }

// ============ pack fp32 weight mats -> f16x2 in ws (Whh x4, Wih x4, Wm, Wlv, Wl2h) ============
struct PackArgs { const float2* src[11]; int end[11]; };

__global__ __launch_bounds__(256) void k_pack(PackArgs pa, h2_t* dst, int total){
  int idx = blockIdx.x*256 + threadIdx.x;
  if (idx >= total) return;
  int m = 0, start = 0;
  #pragma unroll
  for (int k=0;k<11;k++){ if (idx >= pa.end[k]) { m = k+1; start = pa.end[k]; } }
  float2 f = pa.src[m][idx - start];
  h2_t r; r.x = (_Float16)f.x; r.y = (_Float16)f.y;
  dst[idx] = r;
}

// ============ gi[g][l][b][768] = emb[nodes[l,b]] @ Wih_g^T + bih_g  (stored f16) ============
struct GiArgs { const float* bih[4]; };

__global__ __launch_bounds__(256) void k_gi(const int* __restrict__ nodes,
                                            const float* __restrict__ emb,
                                            const h2_t* __restrict__ wih2,
                                            GiArgs ga, h2_t* __restrict__ gi2){
  int l = blockIdx.x, g = blockIdx.y, t = threadIdx.x;
  __shared__ __align__(16) h2_t x2[B_SZ*132];   // [b][k2], stride 132 (pad)
  #pragma unroll
  for (int it=0; it<16; ++it){
    int lin = it*256 + t;
    int bb = lin >> 7, k2 = lin & 127;
    int node = nodes[l*B_SZ + bb];
    float2 f = ((const float2*)(emb + (size_t)node*H_SZ))[k2];
    h2_t r; r.x=(_Float16)f.x; r.y=(_Float16)f.y;
    x2[bb*132 + k2] = r;
  }
  __syncthreads();
  const h2_t* W = wih2 + g*98304;
  const float* bih = ga.bih[g];
  for (int jc=0; jc<3; ++jc){
    int j = jc*256 + t;                 // this thread computes gate-row j for all 32 b
    float acc[32];
    #pragma unroll
    for (int bb=0;bb<32;bb++) acc[bb]=0.f;
    const h2_t* Wj = W + j*H2;
    #pragma unroll 4
    for (int k2=0;k2<H2;k2++){
      h2_t w = Wj[k2];
      #pragma unroll
      for (int bb=0;bb<32;bb++) acc[bb] = fdot2(x2[bb*132+k2], w, acc[bb]);
    }
    float bv = bih[j];
    int base = (g*2048 + l*B_SZ)*384 + (j>>1);
    #pragma unroll
    for (int bb=0;bb<32;bb++){
      float own = acc[bb] + bv;
      float oth = __shfl_xor(own, 1, 64);   // pair rows (2m, 2m+1)
      if (!(t&1)){
        h2_t r; r.x=(_Float16)own; r.y=(_Float16)oth;
        gi2[base + bb*384] = r;
      }
    }
  }
}

// ============ sequential scan: encoder -> latent -> decoder. one block per b ============
struct ScanArgs {
  const float* bhh[4];
  const float* b_mean; const float* b_logv; const float* b_l2h;
  const float* enc_init; const float* eps;
};

__global__ __launch_bounds__(768) void k_scan(const int* __restrict__ edges, ScanArgs sa,
                                              const h2_t* __restrict__ wsh,
                                              h2_t* __restrict__ outs2,
                                              float* __restrict__ out){
  int b = blockIdx.x, t = threadIdx.x;
  int i = t & 255, gate = t >> 8;       // thread owns Whh row t of the selected GRU
  __shared__ float h_lds[H_SZ];
  __shared__ __align__(16) h2_t h2[H2];
  __shared__ float g_lds[512];          // z,n pre-activations from threads 256..767
  const _Float16* gi_all = (const _Float16*)(wsh + GI2_OFF);

  if (t < H_SZ) h_lds[t] = sa.enc_init[b*H_SZ + t];
  __syncthreads();
  if (t < H2){ h2_t r; r.x=(_Float16)h_lds[2*t]; r.y=(_Float16)h_lds[2*t+1]; h2[t]=r; }
  __syncthreads();

  for (int ph=0; ph<2; ++ph){
    for (int l=0; l<L_STEPS; ++l){
      int e = edges[l*B_SZ + b];
      int gsel = (ph ? 2 : 0) + (e ? 0 : 1);   // edge!=0 -> child params
      const h2_t* W = wsh + WHH2_OFF + gsel*98304 + t*H2;
      float acc = 0.f;
      #pragma unroll 8
      for (int k2=0;k2<H2;k2++) acc = fdot2(h2[k2], W[k2], acc);
      acc += sa.bhh[gsel][t];
      if (gate) g_lds[(gate-1)*256 + i] = acc;
      __syncthreads();
      if (t < H_SZ){
        const _Float16* gr = gi_all + (size_t)(gsel*2048 + l*B_SZ + b)*G3H;
        float r = sigm((float)gr[i]     + acc);           // ir+hr (own dot = r-row)
        float z = sigm((float)gr[256+i] + g_lds[i]);      // iz+hz
        float n = tanhf((float)gr[512+i] + r*g_lds[256+i]); // inn + r*(hn+bhh_n)
        h_lds[i] = (1.f - z)*n + z*h_lds[i];
      }
      __syncthreads();
      h2_t pk;
      if (t < H2){ pk.x=(_Float16)h_lds[2*t]; pk.y=(_Float16)h_lds[2*t+1]; h2[t]=pk; }
      __syncthreads();
      if (ph==1 && t < H2) outs2[(l*B_SZ + b)*H2 + t] = pk;
    }

    if (ph == 0){
      // latent: mean/logv/z/h0 — per-b local
      if (t < H_SZ){
        const h2_t* Wm = wsh + WM2_OFF  + t*H2;
        const h2_t* Wl = wsh + WLV2_OFF + t*H2;
        float am=0.f, al=0.f;
        #pragma unroll 8
        for (int k2=0;k2<H2;k2++){ am = fdot2(h2[k2], Wm[k2], am); al = fdot2(h2[k2], Wl[k2], al); }
        am += sa.b_mean[t]; al += sa.b_logv[t];
        float zv = sa.eps[b*Z_SZ + t] * __expf(0.5f*al) + am;
        out[OUT_MEAN_OFF + b*Z_SZ + t] = am;
        out[OUT_LOGV_OFF + b*Z_SZ + t] = al;
        out[OUT_Z_OFF    + b*Z_SZ + t] = zv;
        h_lds[t] = zv;
      }
      __syncthreads();
      if (t < H2){ h2_t r; r.x=(_Float16)h_lds[2*t]; r.y=(_Float16)h_lds[2*t+1]; h2[t]=r; }
      __syncthreads();
      float h0v = 0.f;
      if (t < H_SZ){
        const h2_t* Wz = wsh + WL2H2_OFF + t*H2;
        #pragma unroll 8
        for (int k2=0;k2<H2;k2++) h0v = fdot2(h2[k2], Wz[k2], h0v);
        h0v += sa.b_l2h[t];
      }
      __syncthreads();
      if (t < H_SZ) h_lds[t] = h0v;
      __syncthreads();
      if (t < H2){ h2_t r; r.x=(_Float16)h_lds[2*t]; r.y=(_Float16)h_lds[2*t+1]; h2[t]=r; }
      __syncthreads();
    }
  }
}

// ============ logits = outs @ W_voc^T + b_voc  (fp32 out into d_out) ============
// M=2048 (128/blk), N=32000 (256/blk), K2=128. fdot2 register tile 8x8. W_voc converted fp32->f16 in staging.
__global__ __launch_bounds__(512) void k_gemm(const h2_t* __restrict__ outs2,
                                              const float* __restrict__ wv,
                                              const float* __restrict__ bvoc,
                                              float* __restrict__ outf){
  int t = threadIdx.x;
  int vq = t & 31, rq = t >> 5;          // rq 0..15
  int Nb = blockIdx.x * 256, Mb = blockIdx.y * 128;
  __shared__ __align__(16) h2_t A[16*128];    // [k2][r]
  __shared__ __align__(16) h2_t Bs[16*256];   // [k2][v]
  float acc[8][8];
  #pragma unroll
  for (int a=0;a<8;a++){
    #pragma unroll
    for (int c=0;c<8;c++) acc[a][c]=0.f;
  }

  for (int kc=0;kc<8;kc++){
    { // stage A: 128 r x 16 k2 from f16-packed outs2
      int r = t >> 2, q = t & 3;
      union{float4 f; h2_t h[4];} u;
      u.f = ((const float4*)(outs2 + (Mb + r)*H2 + kc*16))[q];
      #pragma unroll
      for (int uu=0; uu<4; ++uu) A[(q*4+uu)*128 + r] = u.h[uu];
    }
    { // stage B: 256 v x 16 k2, converting fp32 W_voc on the fly
      int v = t >> 1, q = t & 1;
      const float* wrow = wv + (size_t)(Nb + v)*H_SZ + kc*32 + q*16;
      #pragma unroll
      for (int p=0;p<4;p++){
        float4 f = ((const float4*)wrow)[p];
        h2_t h0; h0.x=(_Float16)f.x; h0.y=(_Float16)f.y;
        h2_t h1; h1.x=(_Float16)f.z; h1.y=(_Float16)f.w;
        Bs[(q*8+p*2  )*256 + v] = h0;
        Bs[(q*8+p*2+1)*256 + v] = h1;
      }
    }
    __syncthreads();
    #pragma unroll 2
    for (int k2=0;k2<16;k2++){
      union{float4 f; h2_t h[4];} a0, a1, b0, b1;
      a0.f = *(const float4*)(A  + k2*128 + rq*8);
      a1.f = *(const float4*)(A  + k2*128 + rq*8 + 4);
      b0.f = *(const float4*)(Bs + k2*256 + vq*4);
      b1.f = *(const float4*)(Bs + k2*256 + vq*4 + 128);
      #pragma unroll
      for (int ii=0;ii<8;ii++){
        h2_t av = (ii<4)? a0.h[ii] : a1.h[ii-4];
        #pragma unroll
        for (int jj=0;jj<8;jj++){
          h2_t bv = (jj<4)? b0.h[jj] : b1.h[jj-4];
          acc[ii][jj] = fdot2(av, bv, acc[ii][jj]);
        }
      }
    }
    __syncthreads();
  }

  float bias0[4], bias1[4];
  #pragma unroll
  for (int jj=0;jj<4;jj++){
    bias0[jj] = bvoc[Nb + 4*vq + jj];
    bias1[jj] = bvoc[Nb + 128 + 4*vq + jj];
  }
  #pragma unroll
  for (int ii=0;ii<8;ii++){
    size_t base = (size_t)(Mb + rq*8 + ii)*(size_t)V_SZ + (size_t)Nb;
    float4 o0, o1;
    o0.x = acc[ii][0]+bias0[0]; o0.y = acc[ii][1]+bias0[1];
    o0.z = acc[ii][2]+bias0[2]; o0.w = acc[ii][3]+bias0[3];
    o1.x = acc[ii][4]+bias1[0]; o1.y = acc[ii][5]+bias1[1];
    o1.z = acc[ii][6]+bias1[2]; o1.w = acc[ii][7]+bias1[3];
    *(float4*)(outf + base + 4*vq)       = o0;
    *(float4*)(outf + base + 128 + 4*vq) = o1;
  }
}

// ============ per-row log_softmax in-place over fp32 logits (register-resident row) ============
__global__ __launch_bounds__(256) void k_softmax(float* __restrict__ outf){
  int rrow = blockIdx.x, t = threadIdx.x;
  float4* row = (float4*)(outf + (size_t)rrow * V_SZ);   // 8000 float4
  float4 v[32];
  #pragma unroll
  for (int i=0;i<31;i++) v[i] = row[i*256 + t];
  if (t < 64) v[31] = row[7936 + t];
  else { v[31].x = -1e30f; v[31].y = -1e30f; v[31].z = -1e30f; v[31].w = -1e30f; }

  float m = -1e30f;
  #pragma unroll
  for (int i=0;i<32;i++) m = fmaxf(m, fmaxf(fmaxf(v[i].x, v[i].y), fmaxf(v[i].z, v[i].w)));

  __shared__ float sred[4];
  __shared__ float sbc;
  int wid = t >> 6, lane = t & 63;
  #pragma unroll
  for (int o=32;o;o>>=1) m = fmaxf(m, __shfl_xor(m, o, 64));
  if (lane==0) sred[wid] = m;
  __syncthreads();
  if (t==0) sbc = fmaxf(fmaxf(sred[0],sred[1]), fmaxf(sred[2],sred[3]));
  __syncthreads();
  m = sbc;
  __syncthreads();

  float s = 0.f;
  #pragma unroll
  for (int i=0;i<32;i++){
    s += __expf(v[i].x - m) + __expf(v[i].y - m) + __expf(v[i].z - m) + __expf(v[i].w - m);
  }
  #pragma unroll
  for (int o=32;o;o>>=1) s += __shfl_xor(s, o, 64);
  if (lane==0) sred[wid] = s;
  __syncthreads();
  if (t==0) sbc = sred[0]+sred[1]+sred[2]+sred[3];
  __syncthreads();
  float lse = m + logf(sbc);

  #pragma unroll
  for (int i=0;i<31;i++){
    v[i].x -= lse; v[i].y -= lse; v[i].z -= lse; v[i].w -= lse;
    row[i*256 + t] = v[i];
  }
  if (t < 64){
    v[31].x -= lse; v[31].y -= lse; v[31].z -= lse; v[31].w -= lse;
    row[7936 + t] = v[31];
  }
}

// ============================================================================
extern "C" void kernel_launch(void* const* d_in, const int* in_sizes, int n_in,
                              void* d_out, int out_size, void* d_ws, size_t ws_size,
                              hipStream_t stream){
  const int* nodes = (const int*)d_in[0];
  const int* edges = (const int*)d_in[1];
  h2_t* wsh = (h2_t*)d_ws;
  float* outf = (float*)d_out;

  // ---- pack recurrent + latent weights fp32 -> f16 ----
  PackArgs pa;
  const int srcidx[11] = {6,10,14,18, 5,9,13,17, 21,23,25};
  const int szh2[11]   = {98304,98304,98304,98304, 98304,98304,98304,98304, 32768,32768,32768};
  int e = 0;
  for (int k=0;k<11;k++){ pa.src[k] = (const float2*)d_in[srcidx[k]]; e += szh2[k]; pa.end[k] = e; }
  k_pack<<<dim3(e/256), dim3(256), 0, stream>>>(pa, wsh, e);   // e = 884736, exact multiple

  // ---- gi precompute (f16) ----
  GiArgs ga;
  ga.bih[0]=(const float*)d_in[7];  ga.bih[1]=(const float*)d_in[11];
  ga.bih[2]=(const float*)d_in[15]; ga.bih[3]=(const float*)d_in[19];
  k_gi<<<dim3(64,4), dim3(256), 0, stream>>>(nodes, (const float*)d_in[4], wsh + WIH2_OFF, ga, wsh + GI2_OFF);

  // ---- recurrent scan (enc -> latent -> dec), one block per b ----
  ScanArgs sa;
  sa.bhh[0]=(const float*)d_in[8];  sa.bhh[1]=(const float*)d_in[12];
  sa.bhh[2]=(const float*)d_in[16]; sa.bhh[3]=(const float*)d_in[20];
  sa.b_mean=(const float*)d_in[22]; sa.b_logv=(const float*)d_in[24]; sa.b_l2h=(const float*)d_in[26];
  sa.enc_init=(const float*)d_in[2]; sa.eps=(const float*)d_in[3];
  k_scan<<<dim3(32), dim3(768), 0, stream>>>(edges, sa, wsh, wsh + OUTS2_OFF, outf);

  // ---- vocab projection (fp32 logits into d_out) ----
  k_gemm<<<dim3(125,16), dim3(512), 0, stream>>>(wsh + OUTS2_OFF, (const float*)d_in[27], (const float*)d_in[28], outf);

  // ---- log_softmax in place ----
  k_softmax<<<dim3(2048), dim3(256), 0, stream>>>(outf);
}